// Round 9
// baseline (103.834 us; speedup 1.0000x reference)
//
#include <hip/hip_runtime.h>

#define NROWS 8192
#define DIMX  128              // raw feature dims
#define KB    192              // i8 K: 128 data + 40 one-hot + 3 sqj-encode + 21 pad
#define KSEG  12               // 16B segments per row
#define PTB   24576            // bytes per 128-row panel tile (128*192)
#define NKS   3                // MFMA K-steps of 64
#define NCLS  10
#define GAPV  0.4f
#define DEBIAS 504.03125f      // 2*4*127*127/256 — exact fp32
#define SCL   (-0.0078125f)    // -1/128 — exact fp32
#define RGR   256              // rows per block (4 waves x 64 rows)
#define NRG   (NROWS / RGR)        // 32 rowgroups
#define CHUNK 512              // cols per block
#define NCHUNK (NROWS / CHUNK)     // 16 col-chunks
#define NT    (CHUNK / 16)         // 32 column tiles of 16
#define NBLK  (NRG * NCHUNK)       // 512 gram blocks

typedef __attribute__((ext_vector_type(4))) int i32x4;

__device__ __forceinline__ int q8(float v) {  // round-to-nearest int8 of 16*x
  int q = (int)rintf(16.f * v);
  return q > 127 ? 127 : (q < -127 ? -127 : q);
}

// ---- kernel 1: build i8 PANEL arrays (K=192), sq, confusion, init minmax ----
// Bit-identical to R6 (passing, absmax 0.0).
__global__ __launch_bounds__(256) void prep_k(const float* __restrict__ x,
                                              const int* __restrict__ tgt,
                                              const float* __restrict__ pred,
                                              char* __restrict__ xa,
                                              char* __restrict__ xbm,
                                              float* __restrict__ sq,
                                              int* __restrict__ conf,
                                              int* __restrict__ emin,
                                              int* __restrict__ emax,
                                              unsigned* __restrict__ ctrs) {
  if (blockIdx.x == 0 && threadIdx.x < 3) ctrs[threadIdx.x] = 0u;
  if (threadIdx.x < 4) {  // init atomic mining slots for this block's 4 rows
    const int r = blockIdx.x * 4 + threadIdx.x;
    emin[r] = 0x7FFFFFFF;          // INT_MAX (mined down; ap/same-class side)
    emax[r] = (int)0x80000000;     // INT_MIN (mined up;  an/diff-class side)
  }

  const int wave = threadIdx.x >> 6;
  const int lane = threadIdx.x & 63;
  const int row  = blockIdx.x * 4 + wave;
  const float2 f2 = ((const float2*)(x + (size_t)row * DIMX))[lane];
  float s = f2.x * f2.x + f2.y * f2.y;
  #pragma unroll
  for (int m = 1; m < 64; m <<= 1) s += __shfl_xor(s, m, 64);

  char* basea = xa  + (size_t)(row >> 7) * PTB + (size_t)(row & 127) * 16;
  char* baseb = xbm + (size_t)(row >> 7) * PTB + (size_t)(row & 127) * 16;
  {  // data elems e=2L,2L+1 -> kseg = L>>3, byte (L&7)*2
    const int q0 = q8(f2.x), q1 = q8(f2.y);
    const unsigned short u = (unsigned short)((q0 & 0xFF) | ((q1 & 0xFF) << 8));
    const size_t off = (size_t)(lane >> 3) * 2048 + (lane & 7) * 2;
    *(unsigned short*)(basea + off) = u;
    *(unsigned short*)(baseb + off) = u;
  }
  const int cls = tgt[row];
  if (lane < 32) {  // aug elems e = 128 + j, j = 2*lane, 2*lane+1
    const int j = 2 * lane;
    unsigned short ua, ub;
    if (lane < 20) {               // class one-hot block (4 dims per class)
      const int c = j >> 2;
      const bool hit = (c == cls);
      ua = hit ? (unsigned short)0x7F7F : 0;  // +127,+127
      ub = hit ? (unsigned short)0x8181 : 0;  // -127,-127
    } else if (lane == 20) {       // j=40,41: K-encode dims, A=(127,127)
      const int K = min((int)rintf(128.f * s), 32385);
      const int t = min(K / 127, 254);
      const int b1 = t < 127 ? t : 127;
      const int b2 = t - b1;
      ua = (unsigned short)0x7F7F;
      ub = (unsigned short)(((-b1) & 0xFF) | (((-b2) & 0xFF) << 8));
    } else if (lane == 21) {       // j=42,43: A=(1,0), B=(-r,0)
      const int K = min((int)rintf(128.f * s), 32385);
      const int t = min(K / 127, 254);
      const int r = min(K - 127 * t, 126);
      ua = (unsigned short)0x0001;
      ub = (unsigned short)((-r) & 0xFF);
    } else { ua = 0; ub = 0; }
    const size_t off = (size_t)(8 + (j >> 4)) * 2048 + (j & 15);
    *(unsigned short*)(basea + off) = ua;
    *(unsigned short*)(baseb + off) = ub;
  }

  if (lane == 0) {
    sq[row] = s;
    const float* pp = pred + (size_t)row * NCLS;
    float v[NCLS];
    #pragma unroll
    for (int c = 0; c < NCLS; ++c) v[c] = pp[c];
    float m1 = v[0]; int i1 = 0;
    #pragma unroll
    for (int c = 1; c < NCLS; ++c)
      if (v[c] > m1) { m1 = v[c]; i1 = c; }
    float m2 = -INFINITY, sum = 0.f;
    #pragma unroll
    for (int c = 0; c < NCLS; ++c) {
      sum += __expf(v[c] - m1);
      if (c != i1) m2 = fmaxf(m2, v[c]);
    }
    const float d01 = (1.f - __expf(m2 - m1)) / sum;
    conf[row] = (d01 <= GAPV) || (i1 != cls);
  }
}

// ---- kernel 2: Gram + integer mining + CHEAP last-block loss tail — R9 ----
// R6 loop (depth-1 prefetch) + 2-tile min3 mining (exact). Tail: mining exits
// via device-scope atomics (coherent at the shared point — no fence needed);
// ordering vs g_done needs only s_waitcnt vmcnt(0), NOT __threadfence's
// buffer_wbl2 L2-flush (R3's 35us mistake). 512th block decodes + writes out.
__global__ __launch_bounds__(256)
__attribute__((amdgpu_waves_per_eu(2, 8)))
void gram_k(const char* __restrict__ xa,
            const char* __restrict__ xbm,
            const float* __restrict__ sq,
            const int* __restrict__ conf,
            int* __restrict__ emin,
            int* __restrict__ emax,
            unsigned* __restrict__ ctrs,
            float* __restrict__ out) {
  __shared__ float red[2][4];
  __shared__ unsigned last_flag;
  const int tid  = threadIdx.x;
  const int wave = tid >> 6;
  const int lane = tid & 63;
  const int quad = lane >> 4;   // 0..3
  const int m16  = lane & 15;   // 0..15
  const int bx = blockIdx.x, by = blockIdx.y;

  // A fragments: rows bx*256 + wave*64 + rt*16 + m16, kseg = ks*4 + quad
  i32x4 A[4][NKS];
  #pragma unroll
  for (int rt = 0; rt < 4; ++rt) {
    const int rbase = wave * 64 + rt * 16;               // 0..240 within block rows
    const char* pa = xa + (size_t)(bx * 2 + (rbase >> 7)) * PTB
                        + (size_t)((rbase & 127) + m16) * 16;
    #pragma unroll
    for (int ks = 0; ks < NKS; ++ks)
      A[rt][ks] = *(const i32x4*)(pa + (size_t)(ks * 4 + quad) * 2048);
  }
  #pragma unroll
  for (int rt = 0; rt < 4; ++rt)
    #pragma unroll
    for (int ks = 0; ks < NKS; ++ks)
      asm("" : "+v"(A[rt][ks]));   // keep A resident

  int Emin[4][4], Emax[4][4];
  #pragma unroll
  for (int r = 0; r < 4; ++r)
    #pragma unroll
    for (int q = 0; q < 4; ++q) { Emin[r][q] = 0x7FFFFFFF; Emax[r][q] = (int)0x80000000; }

  // per-lane invariant B base; tile u: addr = bl + (u>>3)*PTB + (u&7)*256 + ks*8192
  const char* bl = xbm + (size_t)(by * 4) * PTB + (size_t)m16 * 16 + (size_t)quad * 2048;

  i32x4 Bc[NKS], Bn[NKS];
  #pragma unroll
  for (int ks = 0; ks < NKS; ++ks) Bc[ks] = *(const i32x4*)(bl + ks * 8192);

  i32x4 accA[4], accB[4];
  for (int s = 0; s < NT / 4; ++s) {        // 8 groups of 4 tiles (2 pairs)
    #pragma unroll
    for (int jt = 0; jt < 4; ++jt) {
      const int u  = s * 4 + jt;
      const int un = (u + 1 < NT) ? u + 1 : NT - 1;   // clamp: last prefetch redundant
      const size_t toff = (size_t)(un >> 3) * PTB + (size_t)(un & 7) * 256;
      #pragma unroll
      for (int ks = 0; ks < NKS; ++ks)
        Bn[ks] = *(const i32x4*)(bl + toff + ks * 8192);

      i32x4 (&acc)[4] = (jt & 1) ? accB : accA;       // compile-time after unroll
      #pragma unroll
      for (int r = 0; r < 4; ++r) acc[r] = (i32x4){0, 0, 0, 0};
      #pragma unroll
      for (int ks = 0; ks < NKS; ++ks)
        #pragma unroll
        for (int r = 0; r < 4; ++r)
          acc[r] = __builtin_amdgcn_mfma_i32_16x16x64_i8(A[r][ks], Bc[ks], acc[r], 0, 0, 0);

      if (jt & 1) {                                   // 2-tile min3/max3 mining
        #pragma unroll
        for (int r = 0; r < 4; ++r)
          #pragma unroll
          for (int q = 0; q < 4; ++q) {
            Emin[r][q] = min(Emin[r][q], min(accA[r][q], accB[r][q]));
            Emax[r][q] = max(Emax[r][q], max(accA[r][q], accB[r][q]));
          }
      }

      #pragma unroll
      for (int ks = 0; ks < NKS; ++ks) Bc[ks] = Bn[ks];   // renamed away by unroll
    }
  }

  // reduce over the 16 cols held across m16 lanes (quad bits preserved)
  #pragma unroll
  for (int m = 1; m <= 8; m <<= 1)
    #pragma unroll
    for (int r = 0; r < 4; ++r)
      #pragma unroll
      for (int q = 0; q < 4; ++q) {
        Emin[r][q] = min(Emin[r][q], __shfl_xor(Emin[r][q], m, 64));
        Emax[r][q] = max(Emax[r][q], __shfl_xor(Emax[r][q], m, 64));
      }

  if (m16 == 0) {  // lanes 0/16/32/48: quad q-block of 4 consecutive rows per r-tile
    const int rowb = bx * RGR + wave * 64 + quad * 4;
    #pragma unroll
    for (int r = 0; r < 4; ++r)
      #pragma unroll
      for (int q = 0; q < 4; ++q) {
        atomicMin(&emin[rowb + r * 16 + q], Emin[r][q]);
        atomicMax(&emax[rowb + r * 16 + q], Emax[r][q]);
      }
  }

  // ---- last-block-done tail (cheap: vmcnt drain, NO threadfence/wbl2) ----
  asm volatile("s_waitcnt vmcnt(0)" ::: "memory");   // own atomics reached coherent point
  __syncthreads();
  if (tid == 0) last_flag = (atomicAdd(&ctrs[0], 1u) == NBLK - 1u) ? 1u : 0u;
  __syncthreads();
  if (last_flag) {   // all blocks' mining atomics complete (each drained pre-increment)
    float ps = 0.f, pc = 0.f;
    #pragma unroll
    for (int i = 0; i < NROWS / 256; ++i) {   // 32 rows/thread, stride-256 coalesced
      const int row = i * 256 + tid;
      const int lo = atomicAdd(&emin[row], 0);   // device-scope RMW reads (R3-proven)
      const int hi = atomicAdd(&emax[row], 0);
      if (conf[row]) {
        const float ap = sqrtf(fmaxf(sq[row] + SCL * (float)lo - DEBIAS, 1e-12f));
        const float an = sqrtf(fmaxf(sq[row] + SCL * (float)hi, 1e-12f));
        ps += fmaxf(ap - an, 0.f);
        pc += 1.f;
      }
    }
    #pragma unroll
    for (int m = 1; m < 64; m <<= 1) {
      ps += __shfl_xor(ps, m, 64);
      pc += __shfl_xor(pc, m, 64);
    }
    if (lane == 0) { red[0][wave] = ps; red[1][wave] = pc; }
    __syncthreads();
    if (tid == 0) {
      const float St = red[0][0] + red[0][1] + red[0][2] + red[0][3];
      const float Ct = red[1][0] + red[1][1] + red[1][2] + red[1][3];
      out[0] = (Ct > 0.f) ? (St / fmaxf(Ct, 1.f)) : 0.f;
    }
  }
}

extern "C" void kernel_launch(void* const* d_in, const int* in_sizes, int n_in,
                              void* d_out, int out_size, void* d_ws, size_t ws_size,
                              hipStream_t stream) {
  const float* x    = (const float*)d_in[0];
  const float* pred = (const float*)d_in[1];
  const int*   tgt  = (const int*)d_in[2];
  float* out = (float*)d_out;

  char* w = (char*)d_ws;
  const size_t arr_bytes = (size_t)NROWS * KB;   // 1.57 MiB each (i8 panel layout)
  char*  xa   = w;
  char*  xbm  = w + arr_bytes;
  float* sq   = (float*)(w + 2 * arr_bytes);
  int*   conf = (int*)(w + 2 * arr_bytes + (size_t)NROWS * 4);
  int*   emin = (int*)(w + 2 * arr_bytes + (size_t)NROWS * 8);
  int*   emax = (int*)(w + 2 * arr_bytes + (size_t)NROWS * 12);
  unsigned* ctrs = (unsigned*)(w + 2 * arr_bytes + (size_t)NROWS * 16);

  hipLaunchKernelGGL(prep_k, dim3(NROWS / 4), dim3(256), 0, stream,
                     x, tgt, pred, xa, xbm, sq, conf, emin, emax, ctrs);
  hipLaunchKernelGGL(gram_k, dim3(NRG, NCHUNK), dim3(256), 0, stream,
                     xa, xbm, sq, conf, emin, emax, ctrs, out);
}

// Round 11
// 96.255 us; speedup vs baseline: 1.0787x; 1.0787x over previous
//
#include <hip/hip_runtime.h>

#define NROWS 8192
#define DIMX  128              // raw feature dims
#define KB    192              // i8 K: 128 data + 40 one-hot + 3 sqj-encode + 21 pad
#define PTB   24576            // bytes per 128-row panel tile (128*192)
#define NKS   3                // MFMA K-steps of 64
#define NCLS  10
#define GAPV  0.4f
#define DEBIAS 504.03125f      // 2*4*127*127/256 — exact fp32
#define SCL   (-0.0078125f)    // -1/128 — exact fp32
#define RGR   128              // gram rows per block (R11: halved -> 1024 blocks TLP)
#define NRG   (NROWS / RGR)        // 64 rowgroups
#define CHUNK 512              // cols per block
#define NCHUNK (NROWS / CHUNK)     // 16 col-chunks
#define NT    (CHUNK / 16)         // 32 column tiles of 16

typedef __attribute__((ext_vector_type(4))) int i32x4;

__device__ __forceinline__ int q8(float v) {  // round-to-nearest int8 of 16*x
  int q = (int)rintf(16.f * v);
  return q > 127 ? 127 : (q < -127 ? -127 : q);
}
__device__ __forceinline__ int pk4(float4 v) {
  return (q8(v.x) & 255) | ((q8(v.y) & 255) << 8) |
         ((q8(v.z) & 255) << 16) | ((q8(v.w) & 255) << 24);
}

// ---- kernel 1: build i8 B panel (K=192), sq, confusion, init minmax ----
// R6 row body (proven absmax 0.0), 8 rows/wave serially -> 256 blocks.
// xa eliminated: gram self-quantizes A from x (R7-proven byte-identical).
__global__ __launch_bounds__(256) void prep_k(const float* __restrict__ x,
                                              const int* __restrict__ tgt,
                                              const float* __restrict__ pred,
                                              char* __restrict__ xbm,
                                              float* __restrict__ sq,
                                              int* __restrict__ conf,
                                              int* __restrict__ emin,
                                              int* __restrict__ emax,
                                              unsigned* __restrict__ ctrs) {
  if (blockIdx.x == 0 && threadIdx.x < 3) ctrs[threadIdx.x] = 0u;
  if (threadIdx.x < 32) {  // init atomic mining slots for this block's 32 rows
    const int r = blockIdx.x * 32 + threadIdx.x;
    emin[r] = 0x7FFFFFFF;          // INT_MAX (mined down; ap/same-class side)
    emax[r] = (int)0x80000000;     // INT_MIN (mined up;  an/diff-class side)
  }

  const int wave = threadIdx.x >> 6;
  const int lane = threadIdx.x & 63;

  for (int r8 = 0; r8 < 8; ++r8) {
    const int row = blockIdx.x * 32 + r8 * 4 + wave;
    const float2 f2 = ((const float2*)(x + (size_t)row * DIMX))[lane];
    float s = f2.x * f2.x + f2.y * f2.y;
    #pragma unroll
    for (int m = 1; m < 64; m <<= 1) s += __shfl_xor(s, m, 64);

    char* baseb = xbm + (size_t)(row >> 7) * PTB + (size_t)(row & 127) * 16;
    {  // data elems e=2L,2L+1 -> kseg = L>>3, byte (L&7)*2
      const int q0 = q8(f2.x), q1 = q8(f2.y);
      const unsigned short u = (unsigned short)((q0 & 0xFF) | ((q1 & 0xFF) << 8));
      const size_t off = (size_t)(lane >> 3) * 2048 + (lane & 7) * 2;
      *(unsigned short*)(baseb + off) = u;
    }
    const int cls = tgt[row];
    if (lane < 32) {  // aug elems e = 128 + j, j = 2*lane, 2*lane+1
      const int j = 2 * lane;
      unsigned short ub;
      if (lane < 20) {               // class one-hot block (4 dims per class)
        ub = ((j >> 2) == cls) ? (unsigned short)0x8181 : 0;  // -127,-127
      } else if (lane == 20) {       // j=40,41: K-encode, B=-(b1,b2)
        const int K = min((int)rintf(128.f * s), 32385);
        const int t = min(K / 127, 254);
        const int b1 = t < 127 ? t : 127;
        const int b2 = t - b1;
        ub = (unsigned short)(((-b1) & 0xFF) | (((-b2) & 0xFF) << 8));
      } else if (lane == 21) {       // j=42,43: B=(-r,0)
        const int K = min((int)rintf(128.f * s), 32385);
        const int t = min(K / 127, 254);
        const int r = min(K - 127 * t, 126);
        ub = (unsigned short)((-r) & 0xFF);
      } else ub = 0;
      const size_t off = (size_t)(8 + (j >> 4)) * 2048 + (j & 15);
      *(unsigned short*)(baseb + off) = ub;
    }

    if (lane == 0) {
      sq[row] = s;
      const float* pp = pred + (size_t)row * NCLS;
      float v[NCLS];
      #pragma unroll
      for (int c = 0; c < NCLS; ++c) v[c] = pp[c];
      float m1 = v[0]; int i1 = 0;
      #pragma unroll
      for (int c = 1; c < NCLS; ++c)
        if (v[c] > m1) { m1 = v[c]; i1 = c; }
      float m2 = -INFINITY, sum = 0.f;
      #pragma unroll
      for (int c = 0; c < NCLS; ++c) {
        sum += __expf(v[c] - m1);
        if (c != i1) m2 = fmaxf(m2, v[c]);
      }
      const float d01 = (1.f - __expf(m2 - m1)) / sum;
      conf[row] = (d01 <= GAPV) || (i1 != cls);
    }
  }
}

// ---- kernel 2: Gram + integer mining — R11: RGR=128, 1024 blocks ----
// R10 diagnosis: every in-loop variant neutral; counters show latency-bound at
// 2 blocks/CU (Occupancy 9-18%, no pipe saturated). This doubles TLP (4-5
// blocks/CU co-resident) and halves per-block A registers. Loop body = R6
// (proven); A self-quantized from x in registers (R7-proven byte-identical).
__global__ __launch_bounds__(256)
__attribute__((amdgpu_waves_per_eu(2, 8)))
void gram_k(const float* __restrict__ x,
            const int* __restrict__ tgt,
            const char* __restrict__ xbm,
            int* __restrict__ emin,
            int* __restrict__ emax) {
  const int tid  = threadIdx.x;
  const int wave = tid >> 6;
  const int lane = tid & 63;
  const int quad = lane >> 4;   // 0..3
  const int m16  = lane & 15;   // 0..15
  const int bx = blockIdx.x, by = blockIdx.y;

  // A: self-quantize 32 rows/wave from x into register fragments
  i32x4 A[2][NKS];
  #pragma unroll
  for (int rt = 0; rt < 2; ++rt) {
    const int row = bx * RGR + wave * 32 + rt * 16 + m16;
    const float4* xr = (const float4*)(x + (size_t)row * DIMX);
    #pragma unroll
    for (int ks = 0; ks < 2; ++ks) {    // data dims ks*64 + quad*16 + 0..15
      const float4* p = xr + ks * 16 + quad * 4;
      i32x4 f;
      #pragma unroll
      for (int w = 0; w < 4; ++w) f[w] = pk4(p[w]);
      A[rt][ks] = f;
    }
    const int cls = tgt[row];           // aug dims 128 + quad*16 + 0..15
    i32x4 a2 = {0, 0, 0, 0};
    if ((cls >> 2) == quad) a2[cls & 3] = 0x7F7F7F7F;   // one-hot +127 x4
    if (quad == 2) a2[2] |= 0x00017F7F;                 // dims 168,169=127; 170=1
    A[rt][2] = a2;
  }
  #pragma unroll
  for (int rt = 0; rt < 2; ++rt)
    #pragma unroll
    for (int ks = 0; ks < NKS; ++ks)
      asm("" : "+v"(A[rt][ks]));   // keep A resident

  int Emin[2][4], Emax[2][4];
  #pragma unroll
  for (int r = 0; r < 2; ++r)
    #pragma unroll
    for (int q = 0; q < 4; ++q) { Emin[r][q] = 0x7FFFFFFF; Emax[r][q] = (int)0x80000000; }

  // per-lane invariant B base; tile u: addr = bl + (u>>3)*PTB + (u&7)*256 + ks*8192
  const char* bl = xbm + (size_t)(by * 4) * PTB + (size_t)m16 * 16 + (size_t)quad * 2048;

  i32x4 Bc[NKS], Bn[NKS];
  #pragma unroll
  for (int ks = 0; ks < NKS; ++ks) Bc[ks] = *(const i32x4*)(bl + ks * 8192);

  for (int s = 0; s < NT / 4; ++s) {        // 8 groups of 4 tiles
    #pragma unroll
    for (int jt = 0; jt < 4; ++jt) {
      const int u  = s * 4 + jt;
      const int un = (u + 1 < NT) ? u + 1 : NT - 1;   // clamp: last prefetch redundant
      const size_t toff = (size_t)(un >> 3) * PTB + (size_t)(un & 7) * 256;
      #pragma unroll
      for (int ks = 0; ks < NKS; ++ks)
        Bn[ks] = *(const i32x4*)(bl + toff + ks * 8192);

      i32x4 acc[2];
      #pragma unroll
      for (int r = 0; r < 2; ++r) acc[r] = (i32x4){0, 0, 0, 0};
      #pragma unroll
      for (int ks = 0; ks < NKS; ++ks)
        #pragma unroll
        for (int r = 0; r < 2; ++r)
          acc[r] = __builtin_amdgcn_mfma_i32_16x16x64_i8(A[r][ks], Bc[ks], acc[r], 0, 0, 0);

      #pragma unroll
      for (int r = 0; r < 2; ++r)
        #pragma unroll
        for (int q = 0; q < 4; ++q) {       // acc = E = 256dot - 64516[same] - K_j
          Emin[r][q] = min(Emin[r][q], acc[r][q]);
          Emax[r][q] = max(Emax[r][q], acc[r][q]);
        }

      #pragma unroll
      for (int ks = 0; ks < NKS; ++ks) Bc[ks] = Bn[ks];   // renamed away by unroll
    }
  }

  // reduce over the 16 cols held across m16 lanes (quad bits preserved)
  #pragma unroll
  for (int m = 1; m <= 8; m <<= 1)
    #pragma unroll
    for (int r = 0; r < 2; ++r)
      #pragma unroll
      for (int q = 0; q < 4; ++q) {
        Emin[r][q] = min(Emin[r][q], __shfl_xor(Emin[r][q], m, 64));
        Emax[r][q] = max(Emax[r][q], __shfl_xor(Emax[r][q], m, 64));
      }

  if (m16 == 0) {  // lanes 0/16/32/48: quad q-block of 4 consecutive rows per r-tile
    const int rowb = bx * RGR + wave * 32 + quad * 4;
    #pragma unroll
    for (int r = 0; r < 2; ++r)
      #pragma unroll
      for (int q = 0; q < 4; ++q) {
        atomicMin(&emin[rowb + r * 16 + q], Emin[r][q]);
        atomicMax(&emax[rowb + r * 16 + q], Emax[r][q]);
      }
  }
}

// ---- kernel 3: per-row decode + loss — bit-identical to R6 (32 blocks) ----
__global__ __launch_bounds__(256) void reduce_k(const int* __restrict__ emin,
                                                const int* __restrict__ emax,
                                                const float* __restrict__ sq,
                                                const int* __restrict__ conf,
                                                unsigned* __restrict__ ctrs,
                                                float* __restrict__ out) {
  __shared__ float red[2][4];
  const int tid = threadIdx.x, bx = blockIdx.x;
  const int wave = tid >> 6, lane = tid & 63;
  const int row = bx * 256 + tid;

  unsigned* g_done = ctrs;
  float*    Ssum   = (float*)(ctrs + 1);
  float*    Csum   = (float*)(ctrs + 2);

  const float hi = SCL * (float)emin[row];   // hardest-positive cand (incl +DEBIAS)
  const float lo = SCL * (float)emax[row];   // hardest-negative cand
  float ps = 0.f, pc = 0.f;
  if (conf[row]) {
    const float ap = sqrtf(fmaxf(sq[row] + hi - DEBIAS, 1e-12f));
    const float an = sqrtf(fmaxf(sq[row] + lo, 1e-12f));
    ps = fmaxf(ap - an, 0.f);
    pc = 1.f;
  }
  #pragma unroll
  for (int m = 1; m < 64; m <<= 1) {
    ps += __shfl_xor(ps, m, 64);
    pc += __shfl_xor(pc, m, 64);
  }
  if (lane == 0) { red[0][wave] = ps; red[1][wave] = pc; }
  __syncthreads();
  if (tid == 0) {
    atomicAdd(Ssum, red[0][0] + red[0][1] + red[0][2] + red[0][3]);
    atomicAdd(Csum, red[1][0] + red[1][1] + red[1][2] + red[1][3]);
    __threadfence();
    if (atomicAdd(g_done, 1u) == 31u) {
      const float St = atomicAdd(Ssum, 0.f);
      const float Ct = atomicAdd(Csum, 0.f);
      out[0] = (Ct > 0.f) ? (St / fmaxf(Ct, 1.f)) : 0.f;
    }
  }
}

extern "C" void kernel_launch(void* const* d_in, const int* in_sizes, int n_in,
                              void* d_out, int out_size, void* d_ws, size_t ws_size,
                              hipStream_t stream) {
  const float* x    = (const float*)d_in[0];
  const float* pred = (const float*)d_in[1];
  const int*   tgt  = (const int*)d_in[2];
  float* out = (float*)d_out;

  char* w = (char*)d_ws;
  const size_t arr_bytes = (size_t)NROWS * KB;   // 1.57 MiB B panel
  char*  xbm  = w;
  float* sq   = (float*)(w + arr_bytes);
  int*   conf = (int*)(w + arr_bytes + (size_t)NROWS * 4);
  int*   emin = (int*)(w + arr_bytes + (size_t)NROWS * 8);
  int*   emax = (int*)(w + arr_bytes + (size_t)NROWS * 12);
  unsigned* ctrs = (unsigned*)(w + arr_bytes + (size_t)NROWS * 16);

  hipLaunchKernelGGL(prep_k, dim3(NROWS / 32), dim3(256), 0, stream,
                     x, tgt, pred, xbm, sq, conf, emin, emax, ctrs);
  hipLaunchKernelGGL(gram_k, dim3(NRG, NCHUNK), dim3(256), 0, stream,
                     x, tgt, xbm, emin, emax);
  hipLaunchKernelGGL(reduce_k, dim3(32), dim3(256), 0, stream,
                     emin, emax, sq, conf, ctrs, out);
}

// Round 12
// 85.390 us; speedup vs baseline: 1.2160x; 1.1272x over previous
//
#include <hip/hip_runtime.h>

#define NROWS 8192
#define DIMX  128              // raw feature dims
#define KB    192              // i8 K: 128 data + 40 one-hot + 3 sqj-encode + 21 pad
#define KSEG  12               // 16B segments per row
#define PTB   24576            // bytes per 128-row panel tile (128*192)
#define NKS   3                // MFMA K-steps of 64
#define NCLS  10
#define GAPV  0.4f
#define DEBIAS 504.03125f      // 2*4*127*127/256 — exact fp32
#define SCL   (-0.0078125f)    // -1/128 — exact fp32
#define RGR   256              // rows per block (4 waves x 64 rows)
#define NRG   (NROWS / RGR)        // 32 rowgroups
#define CHUNK 512              // cols per block
#define NCHUNK (NROWS / CHUNK)     // 16 col-chunks
#define NT    (CHUNK / 16)         // 32 column tiles of 16

typedef __attribute__((ext_vector_type(4))) int i32x4;

__device__ __forceinline__ int q8(float v) {  // round-to-nearest int8 of 16*x
  int q = (int)rintf(16.f * v);
  return q > 127 ? 127 : (q < -127 ? -127 : q);
}

// ---- kernel 1: build i8 PANEL arrays (K=192), sq, confusion, init minmax ----
// Bit-identical to R6/R8 (passing, absmax 0.0).
__global__ __launch_bounds__(256) void prep_k(const float* __restrict__ x,
                                              const int* __restrict__ tgt,
                                              const float* __restrict__ pred,
                                              char* __restrict__ xa,
                                              char* __restrict__ xbm,
                                              float* __restrict__ sq,
                                              int* __restrict__ conf,
                                              int* __restrict__ emin,
                                              int* __restrict__ emax,
                                              unsigned* __restrict__ ctrs) {
  if (blockIdx.x == 0 && threadIdx.x < 3) ctrs[threadIdx.x] = 0u;
  if (threadIdx.x < 4) {  // init atomic mining slots for this block's 4 rows
    const int r = blockIdx.x * 4 + threadIdx.x;
    emin[r] = 0x7FFFFFFF;          // INT_MAX (mined down; ap/same-class side)
    emax[r] = (int)0x80000000;     // INT_MIN (mined up;  an/diff-class side)
  }

  const int wave = threadIdx.x >> 6;
  const int lane = threadIdx.x & 63;
  const int row  = blockIdx.x * 4 + wave;
  const float2 f2 = ((const float2*)(x + (size_t)row * DIMX))[lane];
  float s = f2.x * f2.x + f2.y * f2.y;
  #pragma unroll
  for (int m = 1; m < 64; m <<= 1) s += __shfl_xor(s, m, 64);

  char* basea = xa  + (size_t)(row >> 7) * PTB + (size_t)(row & 127) * 16;
  char* baseb = xbm + (size_t)(row >> 7) * PTB + (size_t)(row & 127) * 16;
  {  // data elems e=2L,2L+1 -> kseg = L>>3, byte (L&7)*2
    const int q0 = q8(f2.x), q1 = q8(f2.y);
    const unsigned short u = (unsigned short)((q0 & 0xFF) | ((q1 & 0xFF) << 8));
    const size_t off = (size_t)(lane >> 3) * 2048 + (lane & 7) * 2;
    *(unsigned short*)(basea + off) = u;
    *(unsigned short*)(baseb + off) = u;
  }
  const int cls = tgt[row];
  if (lane < 32) {  // aug elems e = 128 + j, j = 2*lane, 2*lane+1
    const int j = 2 * lane;
    unsigned short ua, ub;
    if (lane < 20) {               // class one-hot block (4 dims per class)
      const int c = j >> 2;
      const bool hit = (c == cls);
      ua = hit ? (unsigned short)0x7F7F : 0;  // +127,+127
      ub = hit ? (unsigned short)0x8181 : 0;  // -127,-127
    } else if (lane == 20) {       // j=40,41: K-encode dims, A=(127,127)
      const int K = min((int)rintf(128.f * s), 32385);
      const int t = min(K / 127, 254);
      const int b1 = t < 127 ? t : 127;
      const int b2 = t - b1;
      ua = (unsigned short)0x7F7F;
      ub = (unsigned short)(((-b1) & 0xFF) | (((-b2) & 0xFF) << 8));
    } else if (lane == 21) {       // j=42,43: A=(1,0), B=(-r,0)
      const int K = min((int)rintf(128.f * s), 32385);
      const int t = min(K / 127, 254);
      const int r = min(K - 127 * t, 126);
      ua = (unsigned short)0x0001;
      ub = (unsigned short)((-r) & 0xFF);
    } else { ua = 0; ub = 0; }
    const size_t off = (size_t)(8 + (j >> 4)) * 2048 + (j & 15);
    *(unsigned short*)(basea + off) = ua;
    *(unsigned short*)(baseb + off) = ub;
  }

  if (lane == 0) {
    sq[row] = s;
    const float* pp = pred + (size_t)row * NCLS;
    float v[NCLS];
    #pragma unroll
    for (int c = 0; c < NCLS; ++c) v[c] = pp[c];
    float m1 = v[0]; int i1 = 0;
    #pragma unroll
    for (int c = 1; c < NCLS; ++c)
      if (v[c] > m1) { m1 = v[c]; i1 = c; }
    float m2 = -INFINITY, sum = 0.f;
    #pragma unroll
    for (int c = 0; c < NCLS; ++c) {
      sum += __expf(v[c] - m1);
      if (c != i1) m2 = fmaxf(m2, v[c]);
    }
    const float d01 = (1.f - __expf(m2 - m1)) / sum;
    conf[row] = (d01 <= GAPV) || (i1 != cls);
  }
}

// ---- kernel 2: Gram + integer mining — R12: COPY-FREE ring prefetch ----
// R5/R6/R8 all rotated B via register copies (Bc=Bn...). A copy consuming a
// just-issued load forces s_waitcnt vmcnt(0) EVERY tile, so prefetch depth
// never materialized (why R8's depth-2 was neutral). Ring of 4 slots, tile u
// uses slot u&3 (=jt, static after unroll), prefetch u+2 into (u+2)&3 (also
// static): no copies -> counted vmcnt(N) waits, loads ride ~480cy ahead.
__global__ __launch_bounds__(256)
__attribute__((amdgpu_waves_per_eu(2, 8)))
void gram_k(const char* __restrict__ xa,
            const char* __restrict__ xbm,
            int* __restrict__ emin,
            int* __restrict__ emax) {
  const int tid  = threadIdx.x;
  const int wave = tid >> 6;
  const int lane = tid & 63;
  const int quad = lane >> 4;   // 0..3
  const int m16  = lane & 15;   // 0..15
  const int bx = blockIdx.x, by = blockIdx.y;

  // A fragments: rows bx*256 + wave*64 + rt*16 + m16, kseg = ks*4 + quad
  i32x4 A[4][NKS];
  #pragma unroll
  for (int rt = 0; rt < 4; ++rt) {
    const int rbase = wave * 64 + rt * 16;               // 0..240 within block rows
    const char* pa = xa + (size_t)(bx * 2 + (rbase >> 7)) * PTB
                        + (size_t)((rbase & 127) + m16) * 16;
    #pragma unroll
    for (int ks = 0; ks < NKS; ++ks)
      A[rt][ks] = *(const i32x4*)(pa + (size_t)(ks * 4 + quad) * 2048);
  }
  #pragma unroll
  for (int rt = 0; rt < 4; ++rt)
    #pragma unroll
    for (int ks = 0; ks < NKS; ++ks)
      asm("" : "+v"(A[rt][ks]));   // keep A resident

  int Emin[4][4], Emax[4][4];
  #pragma unroll
  for (int r = 0; r < 4; ++r)
    #pragma unroll
    for (int q = 0; q < 4; ++q) { Emin[r][q] = 0x7FFFFFFF; Emax[r][q] = (int)0x80000000; }

  // per-lane invariant B base; tile u: addr = bl + (u>>3)*PTB + (u&7)*256 + ks*8192
  const char* bl = xbm + (size_t)(by * 4) * PTB + (size_t)m16 * 16 + (size_t)quad * 2048;
  #define BTOFF(u) ((size_t)((u) >> 3) * PTB + (size_t)((u) & 7) * 256)

  i32x4 Bring[4][NKS];   // ring slots; all indices compile-time after unroll
  #pragma unroll
  for (int ks = 0; ks < NKS; ++ks) Bring[0][ks] = *(const i32x4*)(bl + BTOFF(0) + ks * 8192);
  #pragma unroll
  for (int ks = 0; ks < NKS; ++ks) Bring[1][ks] = *(const i32x4*)(bl + BTOFF(1) + ks * 8192);

  for (int s = 0; s < NT / 4; ++s) {        // 8 groups of 4 tiles
    #pragma unroll
    for (int jt = 0; jt < 4; ++jt) {        // slot(u)=jt, prefetch slot=(jt+2)&3
      const int u  = s * 4 + jt;
      const int up = (u + 2 < NT) ? u + 2 : NT - 1;   // clamp: tail prefetch redundant
      const size_t toff = BTOFF(up);
      #pragma unroll
      for (int ks = 0; ks < NKS; ++ks)
        Bring[(jt + 2) & 3][ks] = *(const i32x4*)(bl + toff + ks * 8192);

      i32x4 acc[4];
      #pragma unroll
      for (int r = 0; r < 4; ++r) acc[r] = (i32x4){0, 0, 0, 0};
      #pragma unroll
      for (int ks = 0; ks < NKS; ++ks)
        #pragma unroll
        for (int r = 0; r < 4; ++r)
          acc[r] = __builtin_amdgcn_mfma_i32_16x16x64_i8(A[r][ks], Bring[jt][ks], acc[r], 0, 0, 0);

      #pragma unroll
      for (int r = 0; r < 4; ++r)
        #pragma unroll
        for (int q = 0; q < 4; ++q) {       // acc = E = 256dot - 64516[same] - K_j
          Emin[r][q] = min(Emin[r][q], acc[r][q]);
          Emax[r][q] = max(Emax[r][q], acc[r][q]);
        }
    }
  }

  // reduce over the 16 cols held across m16 lanes (quad bits preserved)
  #pragma unroll
  for (int m = 1; m <= 8; m <<= 1)
    #pragma unroll
    for (int r = 0; r < 4; ++r)
      #pragma unroll
      for (int q = 0; q < 4; ++q) {
        Emin[r][q] = min(Emin[r][q], __shfl_xor(Emin[r][q], m, 64));
        Emax[r][q] = max(Emax[r][q], __shfl_xor(Emax[r][q], m, 64));
      }

  if (m16 == 0) {  // lanes 0/16/32/48: quad q-block of 4 consecutive rows per r-tile
    const int rowb = bx * RGR + wave * 64 + quad * 4;
    #pragma unroll
    for (int r = 0; r < 4; ++r)
      #pragma unroll
      for (int q = 0; q < 4; ++q) {
        atomicMin(&emin[rowb + r * 16 + q], Emin[r][q]);
        atomicMax(&emax[rowb + r * 16 + q], Emax[r][q]);
      }
  }
}

// ---- kernel 3: per-row decode + loss — bit-identical to R6/R8 ----
__global__ __launch_bounds__(256) void reduce_k(const int* __restrict__ emin,
                                                const int* __restrict__ emax,
                                                const float* __restrict__ sq,
                                                const int* __restrict__ conf,
                                                unsigned* __restrict__ ctrs,
                                                float* __restrict__ out) {
  __shared__ float red[2][4];
  const int tid = threadIdx.x, bx = blockIdx.x;
  const int wave = tid >> 6, lane = tid & 63;
  const int row = bx * RGR + tid;

  unsigned* g_done = ctrs;
  float*    Ssum   = (float*)(ctrs + 1);
  float*    Csum   = (float*)(ctrs + 2);

  const float hi = SCL * (float)emin[row];   // hardest-positive cand (incl +DEBIAS)
  const float lo = SCL * (float)emax[row];   // hardest-negative cand
  float ps = 0.f, pc = 0.f;
  if (conf[row]) {
    const float ap = sqrtf(fmaxf(sq[row] + hi - DEBIAS, 1e-12f));
    const float an = sqrtf(fmaxf(sq[row] + lo, 1e-12f));
    ps = fmaxf(ap - an, 0.f);
    pc = 1.f;
  }
  #pragma unroll
  for (int m = 1; m < 64; m <<= 1) {
    ps += __shfl_xor(ps, m, 64);
    pc += __shfl_xor(pc, m, 64);
  }
  if (lane == 0) { red[0][wave] = ps; red[1][wave] = pc; }
  __syncthreads();
  if (tid == 0) {
    atomicAdd(Ssum, red[0][0] + red[0][1] + red[0][2] + red[0][3]);
    atomicAdd(Csum, red[1][0] + red[1][1] + red[1][2] + red[1][3]);
    __threadfence();
    if (atomicAdd(g_done, 1u) == NRG - 1u) {
      const float St = atomicAdd(Ssum, 0.f);
      const float Ct = atomicAdd(Csum, 0.f);
      out[0] = (Ct > 0.f) ? (St / fmaxf(Ct, 1.f)) : 0.f;
    }
  }
}

extern "C" void kernel_launch(void* const* d_in, const int* in_sizes, int n_in,
                              void* d_out, int out_size, void* d_ws, size_t ws_size,
                              hipStream_t stream) {
  const float* x    = (const float*)d_in[0];
  const float* pred = (const float*)d_in[1];
  const int*   tgt  = (const int*)d_in[2];
  float* out = (float*)d_out;

  char* w = (char*)d_ws;
  const size_t arr_bytes = (size_t)NROWS * KB;   // 1.57 MiB each (i8 panel layout)
  char*  xa   = w;
  char*  xbm  = w + arr_bytes;
  float* sq   = (float*)(w + 2 * arr_bytes);
  int*   conf = (int*)(w + 2 * arr_bytes + (size_t)NROWS * 4);
  int*   emin = (int*)(w + 2 * arr_bytes + (size_t)NROWS * 8);
  int*   emax = (int*)(w + 2 * arr_bytes + (size_t)NROWS * 12);
  unsigned* ctrs = (unsigned*)(w + 2 * arr_bytes + (size_t)NROWS * 16);

  hipLaunchKernelGGL(prep_k, dim3(NROWS / 4), dim3(256), 0, stream,
                     x, tgt, pred, xa, xbm, sq, conf, emin, emax, ctrs);
  hipLaunchKernelGGL(gram_k, dim3(NRG, NCHUNK), dim3(256), 0, stream,
                     xa, xbm, emin, emax);
  hipLaunchKernelGGL(reduce_k, dim3(NRG), dim3(256), 0, stream,
                     emin, emax, sq, conf, ctrs, out);
}

// Round 13
// 83.825 us; speedup vs baseline: 1.2387x; 1.0187x over previous
//
#include <hip/hip_runtime.h>

#define NROWS 8192
#define DIMX  128              // raw feature dims
#define KB    192              // i8 K: 128 data + 40 one-hot + 3 sqj-encode + 21 pad
#define KSEG  12               // 16B segments per row
#define PTB   24576            // bytes per 128-row panel tile (128*192)
#define NKS   3                // MFMA K-steps of 64
#define NCLS  10
#define GAPV  0.4f
#define DEBIAS 504.03125f      // 2*4*127*127/256 — exact fp32
#define SCL   (-0.0078125f)    // -1/128 — exact fp32
#define RGR   256              // rows per block (4 waves x 64 rows)
#define NRG   (NROWS / RGR)        // 32 rowgroups
#define CHUNK 512              // cols per block
#define NCHUNK (NROWS / CHUNK)     // 16 col-chunks
#define NT    (CHUNK / 16)         // 32 column tiles of 16

typedef __attribute__((ext_vector_type(4))) int i32x4;

__device__ __forceinline__ int q8(float v) {  // round-to-nearest int8 of 16*x
  int q = (int)rintf(16.f * v);
  return q > 127 ? 127 : (q < -127 ? -127 : q);
}

// ---- kernel 1: build i8 PANEL arrays (K=192), sq, confusion, init ctrs ----
// Row body bit-identical to R6 (passing, absmax 0.0).
// ctrs: [0]=g_done (decoders), [1]=Ssum, [2]=Csum, [3..34]=done[32] per-rowgroup.
__global__ __launch_bounds__(256) void prep_k(const float* __restrict__ x,
                                              const int* __restrict__ tgt,
                                              const float* __restrict__ pred,
                                              char* __restrict__ xa,
                                              char* __restrict__ xbm,
                                              float* __restrict__ sq,
                                              int* __restrict__ conf,
                                              int* __restrict__ emin,
                                              int* __restrict__ emax,
                                              unsigned* __restrict__ ctrs) {
  if (blockIdx.x == 0 && threadIdx.x < 35) ctrs[threadIdx.x] = 0u;
  if (threadIdx.x < 4) {  // init atomic mining slots for this block's 4 rows
    const int r = blockIdx.x * 4 + threadIdx.x;
    emin[r] = 0x7FFFFFFF;          // INT_MAX (mined down; ap/same-class side)
    emax[r] = (int)0x80000000;     // INT_MIN (mined up;  an/diff-class side)
  }

  const int wave = threadIdx.x >> 6;
  const int lane = threadIdx.x & 63;
  const int row  = blockIdx.x * 4 + wave;
  const float2 f2 = ((const float2*)(x + (size_t)row * DIMX))[lane];
  float s = f2.x * f2.x + f2.y * f2.y;
  #pragma unroll
  for (int m = 1; m < 64; m <<= 1) s += __shfl_xor(s, m, 64);

  char* basea = xa  + (size_t)(row >> 7) * PTB + (size_t)(row & 127) * 16;
  char* baseb = xbm + (size_t)(row >> 7) * PTB + (size_t)(row & 127) * 16;
  {  // data elems e=2L,2L+1 -> kseg = L>>3, byte (L&7)*2
    const int q0 = q8(f2.x), q1 = q8(f2.y);
    const unsigned short u = (unsigned short)((q0 & 0xFF) | ((q1 & 0xFF) << 8));
    const size_t off = (size_t)(lane >> 3) * 2048 + (lane & 7) * 2;
    *(unsigned short*)(basea + off) = u;
    *(unsigned short*)(baseb + off) = u;
  }
  const int cls = tgt[row];
  if (lane < 32) {  // aug elems e = 128 + j, j = 2*lane, 2*lane+1
    const int j = 2 * lane;
    unsigned short ua, ub;
    if (lane < 20) {               // class one-hot block (4 dims per class)
      const int c = j >> 2;
      const bool hit = (c == cls);
      ua = hit ? (unsigned short)0x7F7F : 0;  // +127,+127
      ub = hit ? (unsigned short)0x8181 : 0;  // -127,-127
    } else if (lane == 20) {       // j=40,41: K-encode dims, A=(127,127)
      const int K = min((int)rintf(128.f * s), 32385);
      const int t = min(K / 127, 254);
      const int b1 = t < 127 ? t : 127;
      const int b2 = t - b1;
      ua = (unsigned short)0x7F7F;
      ub = (unsigned short)(((-b1) & 0xFF) | (((-b2) & 0xFF) << 8));
    } else if (lane == 21) {       // j=42,43: A=(1,0), B=(-r,0)
      const int K = min((int)rintf(128.f * s), 32385);
      const int t = min(K / 127, 254);
      const int r = min(K - 127 * t, 126);
      ua = (unsigned short)0x0001;
      ub = (unsigned short)((-r) & 0xFF);
    } else { ua = 0; ub = 0; }
    const size_t off = (size_t)(8 + (j >> 4)) * 2048 + (j & 15);
    *(unsigned short*)(basea + off) = ua;
    *(unsigned short*)(baseb + off) = ub;
  }

  if (lane == 0) {
    sq[row] = s;
    const float* pp = pred + (size_t)row * NCLS;
    float v[NCLS];
    #pragma unroll
    for (int c = 0; c < NCLS; ++c) v[c] = pp[c];
    float m1 = v[0]; int i1 = 0;
    #pragma unroll
    for (int c = 1; c < NCLS; ++c)
      if (v[c] > m1) { m1 = v[c]; i1 = c; }
    float m2 = -INFINITY, sum = 0.f;
    #pragma unroll
    for (int c = 0; c < NCLS; ++c) {
      sum += __expf(v[c] - m1);
      if (c != i1) m2 = fmaxf(m2, v[c]);
    }
    const float d01 = (1.f - __expf(m2 - m1)) / sum;
    conf[row] = (d01 <= GAPV) || (i1 != cls);
  }
}

// ---- kernel 2: Gram + integer mining + DISTRIBUTED per-rowgroup tail — R13 ----
// Loop = R6 verbatim (best, 83.1). Tail: after mining atomics + vmcnt(0)
// (R9-proven atomic->atomic ordering, no wbl2), each block increments
// done[bx]; the 16th finisher of rowgroup bx decodes ITS OWN 256 rows
// (1 row/thread, 2 RMW reads) — overlapped with other rowgroups still
// computing, no global straggler wait (R9's mistake). Last of the 32
// decoders writes out. Removes reduce_k dispatch + boundary.
__global__ __launch_bounds__(256)
__attribute__((amdgpu_waves_per_eu(2, 8)))
void gram_k(const char* __restrict__ xa,
            const char* __restrict__ xbm,
            const float* __restrict__ sq,
            const int* __restrict__ conf,
            int* __restrict__ emin,
            int* __restrict__ emax,
            unsigned* __restrict__ ctrs,
            float* __restrict__ out) {
  __shared__ unsigned rg_last;
  __shared__ float red[2][4];
  const int tid  = threadIdx.x;
  const int wave = tid >> 6;
  const int lane = tid & 63;
  const int quad = lane >> 4;   // 0..3
  const int m16  = lane & 15;   // 0..15
  const int bx = blockIdx.x, by = blockIdx.y;

  // A fragments: rows bx*256 + wave*64 + rt*16 + m16, kseg = ks*4 + quad
  i32x4 A[4][NKS];
  #pragma unroll
  for (int rt = 0; rt < 4; ++rt) {
    const int rbase = wave * 64 + rt * 16;               // 0..240 within block rows
    const char* pa = xa + (size_t)(bx * 2 + (rbase >> 7)) * PTB
                        + (size_t)((rbase & 127) + m16) * 16;
    #pragma unroll
    for (int ks = 0; ks < NKS; ++ks)
      A[rt][ks] = *(const i32x4*)(pa + (size_t)(ks * 4 + quad) * 2048);
  }
  #pragma unroll
  for (int rt = 0; rt < 4; ++rt)
    #pragma unroll
    for (int ks = 0; ks < NKS; ++ks)
      asm("" : "+v"(A[rt][ks]));   // keep A resident

  int Emin[4][4], Emax[4][4];
  #pragma unroll
  for (int r = 0; r < 4; ++r)
    #pragma unroll
    for (int q = 0; q < 4; ++q) { Emin[r][q] = 0x7FFFFFFF; Emax[r][q] = (int)0x80000000; }

  // per-lane invariant B base; tile u: addr = bl + (u>>3)*PTB + (u&7)*256 + ks*8192
  const char* bl = xbm + (size_t)(by * 4) * PTB + (size_t)m16 * 16 + (size_t)quad * 2048;

  i32x4 Bc[NKS], Bn[NKS];
  #pragma unroll
  for (int ks = 0; ks < NKS; ++ks) Bc[ks] = *(const i32x4*)(bl + ks * 8192);

  for (int s = 0; s < NT / 4; ++s) {        // 8 groups of 4 tiles
    #pragma unroll
    for (int jt = 0; jt < 4; ++jt) {
      const int u  = s * 4 + jt;
      const int un = (u + 1 < NT) ? u + 1 : NT - 1;   // clamp: last prefetch redundant
      const size_t toff = (size_t)(un >> 3) * PTB + (size_t)(un & 7) * 256;
      #pragma unroll
      for (int ks = 0; ks < NKS; ++ks)
        Bn[ks] = *(const i32x4*)(bl + toff + ks * 8192);

      i32x4 acc[4];
      #pragma unroll
      for (int r = 0; r < 4; ++r) acc[r] = (i32x4){0, 0, 0, 0};
      #pragma unroll
      for (int ks = 0; ks < NKS; ++ks)
        #pragma unroll
        for (int r = 0; r < 4; ++r)
          acc[r] = __builtin_amdgcn_mfma_i32_16x16x64_i8(A[r][ks], Bc[ks], acc[r], 0, 0, 0);

      #pragma unroll
      for (int r = 0; r < 4; ++r)
        #pragma unroll
        for (int q = 0; q < 4; ++q) {       // acc = E = 256dot - 64516[same] - K_j
          Emin[r][q] = min(Emin[r][q], acc[r][q]);
          Emax[r][q] = max(Emax[r][q], acc[r][q]);
        }

      #pragma unroll
      for (int ks = 0; ks < NKS; ++ks) Bc[ks] = Bn[ks];   // renamed away by unroll
    }
  }

  // reduce over the 16 cols held across m16 lanes (quad bits preserved)
  #pragma unroll
  for (int m = 1; m <= 8; m <<= 1)
    #pragma unroll
    for (int r = 0; r < 4; ++r)
      #pragma unroll
      for (int q = 0; q < 4; ++q) {
        Emin[r][q] = min(Emin[r][q], __shfl_xor(Emin[r][q], m, 64));
        Emax[r][q] = max(Emax[r][q], __shfl_xor(Emax[r][q], m, 64));
      }

  if (m16 == 0) {  // lanes 0/16/32/48: quad q-block of 4 consecutive rows per r-tile
    const int rowb = bx * RGR + wave * 64 + quad * 4;
    #pragma unroll
    for (int r = 0; r < 4; ++r)
      #pragma unroll
      for (int q = 0; q < 4; ++q) {
        atomicMin(&emin[rowb + r * 16 + q], Emin[r][q]);
        atomicMax(&emax[rowb + r * 16 + q], Emax[r][q]);
      }
  }

  // ---- distributed tail: 16th finisher of rowgroup bx decodes rows bx*256.. ----
  asm volatile("s_waitcnt vmcnt(0)" ::: "memory");  // own mining atomics at L2
  __syncthreads();
  if (tid == 0)
    rg_last = (atomicAdd(&ctrs[3 + bx], 1u) == NCHUNK - 1u) ? 1u : 0u;
  __syncthreads();
  if (rg_last) {            // all 16 col-chunks of rowgroup bx have contributed
    const int row = bx * RGR + tid;                 // 1 row/thread, coalesced
    const int lo = atomicAdd(&emin[row], 0);        // RMW reads (R9-proven coherent)
    const int hi = atomicAdd(&emax[row], 0);
    float ps = 0.f, pc = 0.f;
    if (conf[row]) {
      const float ap = sqrtf(fmaxf(sq[row] + SCL * (float)lo - DEBIAS, 1e-12f));
      const float an = sqrtf(fmaxf(sq[row] + SCL * (float)hi, 1e-12f));
      ps = fmaxf(ap - an, 0.f);
      pc = 1.f;
    }
    #pragma unroll
    for (int m = 1; m < 64; m <<= 1) {
      ps += __shfl_xor(ps, m, 64);
      pc += __shfl_xor(pc, m, 64);
    }
    if (lane == 0) { red[0][wave] = ps; red[1][wave] = pc; }
    __syncthreads();
    if (tid == 0) {
      float* Ssum = (float*)(ctrs + 1);
      float* Csum = (float*)(ctrs + 2);
      atomicAdd(Ssum, red[0][0] + red[0][1] + red[0][2] + red[0][3]);
      atomicAdd(Csum, red[1][0] + red[1][1] + red[1][2] + red[1][3]);
      asm volatile("s_waitcnt vmcnt(0)" ::: "memory");  // own adds at L2
      if (atomicAdd(&ctrs[0], 1u) == NRG - 1u) {        // last of the 32 decoders
        const float St = atomicAdd(Ssum, 0.f);
        const float Ct = atomicAdd(Csum, 0.f);
        out[0] = (Ct > 0.f) ? (St / fmaxf(Ct, 1.f)) : 0.f;
      }
    }
  }
}

extern "C" void kernel_launch(void* const* d_in, const int* in_sizes, int n_in,
                              void* d_out, int out_size, void* d_ws, size_t ws_size,
                              hipStream_t stream) {
  const float* x    = (const float*)d_in[0];
  const float* pred = (const float*)d_in[1];
  const int*   tgt  = (const int*)d_in[2];
  float* out = (float*)d_out;

  char* w = (char*)d_ws;
  const size_t arr_bytes = (size_t)NROWS * KB;   // 1.57 MiB each (i8 panel layout)
  char*  xa   = w;
  char*  xbm  = w + arr_bytes;
  float* sq   = (float*)(w + 2 * arr_bytes);
  int*   conf = (int*)(w + 2 * arr_bytes + (size_t)NROWS * 4);
  int*   emin = (int*)(w + 2 * arr_bytes + (size_t)NROWS * 8);
  int*   emax = (int*)(w + 2 * arr_bytes + (size_t)NROWS * 12);
  unsigned* ctrs = (unsigned*)(w + 2 * arr_bytes + (size_t)NROWS * 16);

  hipLaunchKernelGGL(prep_k, dim3(NROWS / 4), dim3(256), 0, stream,
                     x, tgt, pred, xa, xbm, sq, conf, emin, emax, ctrs);
  hipLaunchKernelGGL(gram_k, dim3(NRG, NCHUNK), dim3(256), 0, stream,
                     xa, xbm, sq, conf, emin, emax, ctrs, out);
}

// Round 14
// 82.890 us; speedup vs baseline: 1.2527x; 1.0113x over previous
//
#include <hip/hip_runtime.h>

#define NROWS 8192
#define DIMX  128              // raw feature dims
#define KB    192              // i8 K: 128 data + 40 one-hot + 3 sqj-encode + 21 pad
#define KSEG  12               // 16B segments per row
#define PTB   24576            // bytes per 128-row panel tile (128*192)
#define NKS   3                // MFMA K-steps of 64
#define NCLS  10
#define GAPV  0.4f
#define DEBIAS 504.03125f      // 2*4*127*127/256 — exact fp32
#define SCL   (-0.0078125f)    // -1/128 — exact fp32
#define RGR   256              // rows per block (4 waves x 64 rows)
#define NRG   (NROWS / RGR)        // 32 rowgroups
#define CHUNK 512              // cols per block
#define NCHUNK (NROWS / CHUNK)     // 16 col-chunks
#define NT    (CHUNK / 16)         // 32 column tiles of 16
#define PRW   32               // prep rows per block -> 256 blocks

typedef __attribute__((ext_vector_type(4))) int i32x4;

__device__ __forceinline__ int q8(float v) {  // round-to-nearest int8 of 16*x
  int q = (int)rintf(16.f * v);
  return q > 127 ? 127 : (q < -127 ? -127 : q);
}
__device__ __forceinline__ int pk4(float4 v) {  // 4 floats -> 4 packed q8 bytes
  return (q8(v.x) & 255) | ((q8(v.y) & 255) << 8) |
         ((q8(v.z) & 255) << 16) | ((q8(v.w) & 255) << 24);
}

// ---- kernel 1: COALESCED panel build — R14 ----
// Old prep scattered ~96 2-byte stores per row across 12KB (partial-line
// write-combining hell) from a 2048-block dispatch. New: 256 blocks x 32 rows,
// 8 threads/row (one kseg each): contiguous float4 loads -> quantize -> LDS
// stage -> contiguous 16B stores for data ksegs; row-threads write aug ksegs
// coalesced. Same panel bytes; sq tree order differs (ulp-level, loss-safe).
__global__ __launch_bounds__(256) void prep_k(const float* __restrict__ x,
                                              const int* __restrict__ tgt,
                                              const float* __restrict__ pred,
                                              char* __restrict__ xa,
                                              char* __restrict__ xbm,
                                              float* __restrict__ sq,
                                              int* __restrict__ conf,
                                              int* __restrict__ emin,
                                              int* __restrict__ emax,
                                              unsigned* __restrict__ ctrs) {
  __shared__ char  pan[8 * PRW * 16];   // data ksegs 0..7, 32 rows x 16B = 4 KB
  __shared__ float ssq[PRW];
  const int tid = threadIdx.x;
  const int blk = blockIdx.x;
  if (blk == 0 && tid < 35) ctrs[tid] = 0u;  // g_done, Ssum, Csum, done[32]

  // phase A: quantize. row = tid>>3 (0..31), kseg sg = tid&7 (dims 16sg..16sg+15)
  {
    const int r32 = tid >> 3;
    const int sg  = tid & 7;
    const float4* xr = (const float4*)(x + (size_t)(blk * PRW + r32) * DIMX) + sg * 4;
    float ss = 0.f;
    i32x4 w;
    #pragma unroll
    for (int k = 0; k < 4; ++k) {
      const float4 v = xr[k];
      ss += v.x * v.x + v.y * v.y + v.z * v.z + v.w * v.w;
      w[k] = pk4(v);
    }
    *(i32x4*)&pan[(sg * PRW + r32) * 16] = w;
    ss += __shfl_xor(ss, 1, 64);   // 8-lane group (same row) -> full row sumsq
    ss += __shfl_xor(ss, 2, 64);
    ss += __shfl_xor(ss, 4, 64);
    if (sg == 0) ssq[r32] = ss;
  }
  __syncthreads();

  const int panel = blk >> 2;                 // 4 blocks per 128-row panel
  const int rbase = (blk & 3) * PRW;          // row offset within panel

  // phase B: stream data ksegs to BOTH panels — contiguous 16B stores
  {
    const int kseg = tid >> 5;                // 0..7
    const int r32  = tid & 31;
    const i32x4 w = *(const i32x4*)&pan[(kseg * PRW + r32) * 16];
    const size_t off = (size_t)panel * PTB + (size_t)kseg * 2048 + (size_t)(rbase + r32) * 16;
    *(i32x4*)(xa + off)  = w;
    *(i32x4*)(xbm + off) = w;
  }

  // phase C: aug ksegs 8..11 + sq/conf/minmax-init (one thread per row)
  if (tid < PRW) {
    const int row = blk * PRW + tid;
    const float s = ssq[tid];
    const int cls = tgt[row];
    const int K  = min((int)rintf(128.f * s), 32385);
    const int t2 = min(K / 127, 254);
    const int b1 = t2 < 127 ? t2 : 127;
    const int b2 = t2 - b1;
    const int rr = min(K - 127 * t2, 126);

    i32x4 a8 = {0,0,0,0}, a9 = {0,0,0,0}, a10 = {0,0,0,0}, z = {0,0,0,0};
    i32x4 b8 = {0,0,0,0}, b9 = {0,0,0,0}, b10 = {0,0,0,0};
    if (cls < 4)      { a8[cls]      = 0x7F7F7F7F; b8[cls]      = (int)0x81818181; }
    else if (cls < 8) { a9[cls - 4]  = 0x7F7F7F7F; b9[cls - 4]  = (int)0x81818181; }
    else              { a10[cls - 8] = 0x7F7F7F7F; b10[cls - 8] = (int)0x81818181; }
    a10[2] = 0x00017F7F;   // dims 168,169 = +127; 170 = +1 (A side)
    b10[2] = ((-b1) & 255) | (((-b2) & 255) << 8) | (((-rr) & 255) << 16);

    char* pa = xa  + (size_t)panel * PTB + (size_t)(rbase + tid) * 16;
    char* pb = xbm + (size_t)panel * PTB + (size_t)(rbase + tid) * 16;
    *(i32x4*)(pa +  8 * 2048) = a8;  *(i32x4*)(pb +  8 * 2048) = b8;
    *(i32x4*)(pa +  9 * 2048) = a9;  *(i32x4*)(pb +  9 * 2048) = b9;
    *(i32x4*)(pa + 10 * 2048) = a10; *(i32x4*)(pb + 10 * 2048) = b10;
    *(i32x4*)(pa + 11 * 2048) = z;   *(i32x4*)(pb + 11 * 2048) = z;

    sq[row]   = s;
    emin[row] = 0x7FFFFFFF;
    emax[row] = (int)0x80000000;

    const float* pp = pred + (size_t)row * NCLS;
    float v[NCLS];
    #pragma unroll
    for (int c = 0; c < NCLS; ++c) v[c] = pp[c];
    float m1 = v[0]; int i1 = 0;
    #pragma unroll
    for (int c = 1; c < NCLS; ++c)
      if (v[c] > m1) { m1 = v[c]; i1 = c; }
    float m2 = -INFINITY, sum = 0.f;
    #pragma unroll
    for (int c = 0; c < NCLS; ++c) {
      sum += __expf(v[c] - m1);
      if (c != i1) m2 = fmaxf(m2, v[c]);
    }
    const float d01 = (1.f - __expf(m2 - m1)) / sum;
    conf[row] = (d01 <= GAPV) || (i1 != cls);
  }
}

// ---- kernel 2: Gram + integer mining + distributed tail — R13 verbatim ----
__global__ __launch_bounds__(256)
__attribute__((amdgpu_waves_per_eu(2, 8)))
void gram_k(const char* __restrict__ xa,
            const char* __restrict__ xbm,
            const float* __restrict__ sq,
            const int* __restrict__ conf,
            int* __restrict__ emin,
            int* __restrict__ emax,
            unsigned* __restrict__ ctrs,
            float* __restrict__ out) {
  __shared__ unsigned rg_last;
  __shared__ float red[2][4];
  const int tid  = threadIdx.x;
  const int wave = tid >> 6;
  const int lane = tid & 63;
  const int quad = lane >> 4;   // 0..3
  const int m16  = lane & 15;   // 0..15
  const int bx = blockIdx.x, by = blockIdx.y;

  // A fragments: rows bx*256 + wave*64 + rt*16 + m16, kseg = ks*4 + quad
  i32x4 A[4][NKS];
  #pragma unroll
  for (int rt = 0; rt < 4; ++rt) {
    const int rbase = wave * 64 + rt * 16;               // 0..240 within block rows
    const char* pa = xa + (size_t)(bx * 2 + (rbase >> 7)) * PTB
                        + (size_t)((rbase & 127) + m16) * 16;
    #pragma unroll
    for (int ks = 0; ks < NKS; ++ks)
      A[rt][ks] = *(const i32x4*)(pa + (size_t)(ks * 4 + quad) * 2048);
  }
  #pragma unroll
  for (int rt = 0; rt < 4; ++rt)
    #pragma unroll
    for (int ks = 0; ks < NKS; ++ks)
      asm("" : "+v"(A[rt][ks]));   // keep A resident

  int Emin[4][4], Emax[4][4];
  #pragma unroll
  for (int r = 0; r < 4; ++r)
    #pragma unroll
    for (int q = 0; q < 4; ++q) { Emin[r][q] = 0x7FFFFFFF; Emax[r][q] = (int)0x80000000; }

  // per-lane invariant B base; tile u: addr = bl + (u>>3)*PTB + (u&7)*256 + ks*8192
  const char* bl = xbm + (size_t)(by * 4) * PTB + (size_t)m16 * 16 + (size_t)quad * 2048;

  i32x4 Bc[NKS], Bn[NKS];
  #pragma unroll
  for (int ks = 0; ks < NKS; ++ks) Bc[ks] = *(const i32x4*)(bl + ks * 8192);

  for (int s = 0; s < NT / 4; ++s) {        // 8 groups of 4 tiles
    #pragma unroll
    for (int jt = 0; jt < 4; ++jt) {
      const int u  = s * 4 + jt;
      const int un = (u + 1 < NT) ? u + 1 : NT - 1;   // clamp: last prefetch redundant
      const size_t toff = (size_t)(un >> 3) * PTB + (size_t)(un & 7) * 256;
      #pragma unroll
      for (int ks = 0; ks < NKS; ++ks)
        Bn[ks] = *(const i32x4*)(bl + toff + ks * 8192);

      i32x4 acc[4];
      #pragma unroll
      for (int r = 0; r < 4; ++r) acc[r] = (i32x4){0, 0, 0, 0};
      #pragma unroll
      for (int ks = 0; ks < NKS; ++ks)
        #pragma unroll
        for (int r = 0; r < 4; ++r)
          acc[r] = __builtin_amdgcn_mfma_i32_16x16x64_i8(A[r][ks], Bc[ks], acc[r], 0, 0, 0);

      #pragma unroll
      for (int r = 0; r < 4; ++r)
        #pragma unroll
        for (int q = 0; q < 4; ++q) {       // acc = E = 256dot - 64516[same] - K_j
          Emin[r][q] = min(Emin[r][q], acc[r][q]);
          Emax[r][q] = max(Emax[r][q], acc[r][q]);
        }

      #pragma unroll
      for (int ks = 0; ks < NKS; ++ks) Bc[ks] = Bn[ks];   // renamed away by unroll
    }
  }

  // reduce over the 16 cols held across m16 lanes (quad bits preserved)
  #pragma unroll
  for (int m = 1; m <= 8; m <<= 1)
    #pragma unroll
    for (int r = 0; r < 4; ++r)
      #pragma unroll
      for (int q = 0; q < 4; ++q) {
        Emin[r][q] = min(Emin[r][q], __shfl_xor(Emin[r][q], m, 64));
        Emax[r][q] = max(Emax[r][q], __shfl_xor(Emax[r][q], m, 64));
      }

  if (m16 == 0) {  // lanes 0/16/32/48: quad q-block of 4 consecutive rows per r-tile
    const int rowb = bx * RGR + wave * 64 + quad * 4;
    #pragma unroll
    for (int r = 0; r < 4; ++r)
      #pragma unroll
      for (int q = 0; q < 4; ++q) {
        atomicMin(&emin[rowb + r * 16 + q], Emin[r][q]);
        atomicMax(&emax[rowb + r * 16 + q], Emax[r][q]);
      }
  }

  // ---- distributed tail: 16th finisher of rowgroup bx decodes rows bx*256.. ----
  asm volatile("s_waitcnt vmcnt(0)" ::: "memory");  // own mining atomics at L2
  __syncthreads();
  if (tid == 0)
    rg_last = (atomicAdd(&ctrs[3 + bx], 1u) == NCHUNK - 1u) ? 1u : 0u;
  __syncthreads();
  if (rg_last) {            // all 16 col-chunks of rowgroup bx have contributed
    const int row = bx * RGR + tid;                 // 1 row/thread, coalesced
    const int lo = atomicAdd(&emin[row], 0);        // RMW reads (R9-proven coherent)
    const int hi = atomicAdd(&emax[row], 0);
    float ps = 0.f, pc = 0.f;
    if (conf[row]) {
      const float ap = sqrtf(fmaxf(sq[row] + SCL * (float)lo - DEBIAS, 1e-12f));
      const float an = sqrtf(fmaxf(sq[row] + SCL * (float)hi, 1e-12f));
      ps = fmaxf(ap - an, 0.f);
      pc = 1.f;
    }
    #pragma unroll
    for (int m = 1; m < 64; m <<= 1) {
      ps += __shfl_xor(ps, m, 64);
      pc += __shfl_xor(pc, m, 64);
    }
    if (lane == 0) { red[0][wave] = ps; red[1][wave] = pc; }
    __syncthreads();
    if (tid == 0) {
      float* Ssum = (float*)(ctrs + 1);
      float* Csum = (float*)(ctrs + 2);
      atomicAdd(Ssum, red[0][0] + red[0][1] + red[0][2] + red[0][3]);
      atomicAdd(Csum, red[1][0] + red[1][1] + red[1][2] + red[1][3]);
      asm volatile("s_waitcnt vmcnt(0)" ::: "memory");  // own adds at L2
      if (atomicAdd(&ctrs[0], 1u) == NRG - 1u) {        // last of the 32 decoders
        const float St = atomicAdd(Ssum, 0.f);
        const float Ct = atomicAdd(Csum, 0.f);
        out[0] = (Ct > 0.f) ? (St / fmaxf(Ct, 1.f)) : 0.f;
      }
    }
  }
}

extern "C" void kernel_launch(void* const* d_in, const int* in_sizes, int n_in,
                              void* d_out, int out_size, void* d_ws, size_t ws_size,
                              hipStream_t stream) {
  const float* x    = (const float*)d_in[0];
  const float* pred = (const float*)d_in[1];
  const int*   tgt  = (const int*)d_in[2];
  float* out = (float*)d_out;

  char* w = (char*)d_ws;
  const size_t arr_bytes = (size_t)NROWS * KB;   // 1.57 MiB each (i8 panel layout)
  char*  xa   = w;
  char*  xbm  = w + arr_bytes;
  float* sq   = (float*)(w + 2 * arr_bytes);
  int*   conf = (int*)(w + 2 * arr_bytes + (size_t)NROWS * 4);
  int*   emin = (int*)(w + 2 * arr_bytes + (size_t)NROWS * 8);
  int*   emax = (int*)(w + 2 * arr_bytes + (size_t)NROWS * 12);
  unsigned* ctrs = (unsigned*)(w + 2 * arr_bytes + (size_t)NROWS * 16);

  hipLaunchKernelGGL(prep_k, dim3(NROWS / PRW), dim3(256), 0, stream,
                     x, tgt, pred, xa, xbm, sq, conf, emin, emax, ctrs);
  hipLaunchKernelGGL(gram_k, dim3(NRG, NCHUNK), dim3(256), 0, stream,
                     xa, xbm, sq, conf, emin, emax, ctrs, out);
}